// Round 2
// baseline (840.415 us; speedup 1.0000x reference)
//
#include <hip/hip_runtime.h>

#define B_TOTAL 4096
#define NVARS   128
#define NMOD    128
#define HID     256

typedef __attribute__((ext_vector_type(8))) __bf16 bf16x8;
typedef __attribute__((ext_vector_type(4))) float  f32x4;

__device__ __forceinline__ unsigned short f2bf(float f) {
    unsigned int u = __builtin_bit_cast(unsigned int, f);
    u += 0x7FFFu + ((u >> 16) & 1u);   // round-to-nearest-even
    return (unsigned short)(u >> 16);
}

// ---------------------------------------------------------------------------
// fp32 -> bf16 weight conversion (once per launch; weights then L2/L3-hot)
// ---------------------------------------------------------------------------
__global__ __launch_bounds__(256) void k_cvt(const float* __restrict__ in,
                                             ushort4* __restrict__ out, int n4) {
    int i = blockIdx.x * 256 + threadIdx.x;
    if (i < n4) {
        float4 v = ((const float4*)in)[i];
        ushort4 o;
        o.x = f2bf(v.x); o.y = f2bf(v.y); o.z = f2bf(v.z); o.w = f2bf(v.w);
        out[i] = o;
    }
}

// ---------------------------------------------------------------------------
// Xm[t][b][j] = bf16( mask_n2m[b][j][t] * x[b][j] )
// LDS tile stored as [j][t-pair] u32 (2 bf16 packed, t fast). Row stride 65
// words (odd) -> phase-1 writes conflict-free-minimal, phase-2 reads 4-way.
// ---------------------------------------------------------------------------
__global__ __launch_bounds__(256) void k_maskx(const float* __restrict__ mask,
                                               const float* __restrict__ x,
                                               unsigned short* __restrict__ Xm) {
    const int b = blockIdx.x;
    const int tid = threadIdx.x;
    __shared__ float xs[NVARS];
    __shared__ unsigned int T[NVARS * 65];   // [j][tp], tp = t/2

    if (tid < NVARS) xs[tid] = x[(size_t)b * NVARS + tid];
    __syncthreads();

    const float* mrow = mask + (size_t)b * (NVARS * NMOD);
    // phase 1: coalesced float4 reads (4 consecutive t at fixed j), pack 2x u32
    #pragma unroll
    for (int it = 0; it < 16; ++it) {
        int idx4 = it * 256 + tid;
        int flat = idx4 * 4;
        int j  = flat >> 7;
        int t0 = flat & 127;
        float4 mv = *(const float4*)(mrow + flat);
        float xv = xs[j];
        unsigned int lo = (unsigned int)f2bf(mv.x * xv) | ((unsigned int)f2bf(mv.y * xv) << 16);
        unsigned int hi = (unsigned int)f2bf(mv.z * xv) | ((unsigned int)f2bf(mv.w * xv) << 16);
        T[j * 65 + (t0 >> 1)]     = lo;
        T[j * 65 + (t0 >> 1) + 1] = hi;
    }
    __syncthreads();

    // phase 2: item = (t-pair, 8-j chunk); read 8 u32 down a j-column,
    // split lo/hi halves into two output rows, write 16B coalesced.
    #pragma unroll
    for (int it = 0; it < 4; ++it) {
        int idx = it * 256 + tid;
        int tp = idx >> 4;        // 0..63
        int c  = idx & 15;
        unsigned int r[8];
        #pragma unroll
        for (int k = 0; k < 8; ++k) r[k] = T[(8 * c + k) * 65 + tp];
        uint4 lo4, hi4;
        lo4.x = (r[0] & 0xFFFFu) | (r[1] << 16);
        lo4.y = (r[2] & 0xFFFFu) | (r[3] << 16);
        lo4.z = (r[4] & 0xFFFFu) | (r[5] << 16);
        lo4.w = (r[6] & 0xFFFFu) | (r[7] << 16);
        hi4.x = (r[0] >> 16) | (r[1] & 0xFFFF0000u);
        hi4.y = (r[2] >> 16) | (r[3] & 0xFFFF0000u);
        hi4.z = (r[4] >> 16) | (r[5] & 0xFFFF0000u);
        hi4.w = (r[6] >> 16) | (r[7] & 0xFFFF0000u);
        size_t base0 = ((size_t)(2 * tp)     * B_TOTAL + b) * NVARS + c * 8;
        size_t base1 = ((size_t)(2 * tp + 1) * B_TOTAL + b) * NVARS + c * 8;
        *(uint4*)(Xm + base0) = lo4;
        *(uint4*)(Xm + base1) = hi4;
    }
}

// ---------------------------------------------------------------------------
// Fused 3-layer per-module MLP.  block = (module t, 64-row batch tile)
// sA (17 KB) aliases into sH (33.8 KB): LDS 34.8 KB -> 4 blocks/CU.
// MFMA 16x16x32 bf16 layouts (m89/m91-verified):
//   A/B: lane l -> row (l&15), k = (l>>4)*8 + j (8 contiguous)
//   C/D: lane l, reg r -> row (l>>4)*4 + r, col (l&15)
// ---------------------------------------------------------------------------
__global__ __launch_bounds__(256, 4) void k_mlp(
    const unsigned short* __restrict__ Xm,   // [128][4096][128] bf16
    const unsigned short* __restrict__ W0b,  // [128][256][128] bf16
    const float* __restrict__ b0,            // [128][256]
    const unsigned short* __restrict__ W1b,  // [128][256][256] bf16
    const float* __restrict__ b1,            // [128][256]
    const float* __restrict__ W2,            // [128][256]
    const float* __restrict__ b2,            // [128]
    float* __restrict__ hout)                // [4096][128]
{
    const int t     = blockIdx.y;
    const int brow0 = blockIdx.x * 64;
    const int tid   = threadIdx.x;
    const int w     = tid >> 6;
    const int l     = tid & 63;
    const int quad  = l >> 4;
    const int l16   = l & 15;

    __shared__ __align__(16) unsigned short smem[64 * 264];  // sH; sA aliases front
    __shared__ float hpart[4][64];
    unsigned short* sA = smem;   // stride 136 (uses 17408 B)
    unsigned short* sH = smem;   // stride 264 (uses 33792 B)

    // ---- stage Xm tile: 64 rows x 128 bf16, coalesced 16B chunks ----
    {
        const unsigned short* xsrc = Xm + ((size_t)t * B_TOTAL + brow0) * NVARS;
        #pragma unroll
        for (int it = 0; it < 4; ++it) {
            int idx = it * 256 + tid;
            int r = idx >> 4;
            int c = idx & 15;
            uint4 v = *(const uint4*)(xsrc + (size_t)r * NVARS + c * 8);
            *(uint4*)(sA + r * 136 + c * 8) = v;
        }
    }
    __syncthreads();

    // ---- layer 0 ----
    f32x4 acc[4][4];
    #pragma unroll
    for (int mi = 0; mi < 4; ++mi)
        #pragma unroll
        for (int ni = 0; ni < 4; ++ni)
            acc[mi][ni] = {0.f, 0.f, 0.f, 0.f};

    const unsigned short* w0p = W0b + (size_t)t * HID * NVARS;
    #pragma unroll
    for (int k0 = 0; k0 < NVARS; k0 += 32) {
        bf16x8 a[4];
        #pragma unroll
        for (int mi = 0; mi < 4; ++mi)
            a[mi] = *(const bf16x8*)(sA + (mi * 16 + l16) * 136 + k0 + quad * 8);
        #pragma unroll
        for (int ni = 0; ni < 4; ++ni) {
            int n = w * 64 + ni * 16 + l16;
            bf16x8 bb = *(const bf16x8*)(w0p + n * NVARS + k0 + quad * 8);
            #pragma unroll
            for (int mi = 0; mi < 4; ++mi)
                acc[mi][ni] = __builtin_amdgcn_mfma_f32_16x16x32_bf16(a[mi], bb, acc[mi][ni], 0, 0, 0);
        }
    }
    __syncthreads();   // all waves done reading sA before sH overwrites it

    // ---- epilogue 0: bias + lrelu -> sH (bf16) ----
    {
        float b0v[4];
        #pragma unroll
        for (int ni = 0; ni < 4; ++ni)
            b0v[ni] = b0[t * HID + w * 64 + ni * 16 + l16];
        #pragma unroll
        for (int mi = 0; mi < 4; ++mi) {
            int row = mi * 16 + quad * 4;
            #pragma unroll
            for (int ni = 0; ni < 4; ++ni) {
                int col = w * 64 + ni * 16 + l16;
                #pragma unroll
                for (int r = 0; r < 4; ++r) {
                    float v = acc[mi][ni][r] + b0v[ni];
                    v = v > 0.f ? v : 0.01f * v;
                    sH[(row + r) * 264 + col] = f2bf(v);
                }
            }
        }
    }
    __syncthreads();

    // ---- layer 1 ----
    #pragma unroll
    for (int mi = 0; mi < 4; ++mi)
        #pragma unroll
        for (int ni = 0; ni < 4; ++ni)
            acc[mi][ni] = {0.f, 0.f, 0.f, 0.f};

    const unsigned short* w1p = W1b + (size_t)t * HID * HID;
    #pragma unroll
    for (int k0 = 0; k0 < HID; k0 += 32) {
        bf16x8 a[4];
        #pragma unroll
        for (int mi = 0; mi < 4; ++mi)
            a[mi] = *(const bf16x8*)(sH + (mi * 16 + l16) * 264 + k0 + quad * 8);
        #pragma unroll
        for (int ni = 0; ni < 4; ++ni) {
            int n = w * 64 + ni * 16 + l16;
            bf16x8 bb = *(const bf16x8*)(w1p + n * HID + k0 + quad * 8);
            #pragma unroll
            for (int mi = 0; mi < 4; ++mi)
                acc[mi][ni] = __builtin_amdgcn_mfma_f32_16x16x32_bf16(a[mi], bb, acc[mi][ni], 0, 0, 0);
        }
    }

    // ---- epilogue 1: bias + lrelu, dot with W2 in-register, reduce over l16 ----
    {
        float b1v[4], w2v[4];
        #pragma unroll
        for (int ni = 0; ni < 4; ++ni) {
            int n = t * HID + w * 64 + ni * 16 + l16;
            b1v[ni] = b1[n];
            w2v[ni] = W2[n];
        }
        #pragma unroll
        for (int mi = 0; mi < 4; ++mi) {
            #pragma unroll
            for (int r = 0; r < 4; ++r) {
                float s = 0.f;
                #pragma unroll
                for (int ni = 0; ni < 4; ++ni) {
                    float v = acc[mi][ni][r] + b1v[ni];
                    v = v > 0.f ? v : 0.01f * v;
                    s += v * w2v[ni];
                }
                s += __shfl_xor(s, 1, 64);
                s += __shfl_xor(s, 2, 64);
                s += __shfl_xor(s, 4, 64);
                s += __shfl_xor(s, 8, 64);
                if (l16 == 0) hpart[w][mi * 16 + quad * 4 + r] = s;
            }
        }
    }
    __syncthreads();

    if (tid < 64) {
        float hv = hpart[0][tid] + hpart[1][tid] + hpart[2][tid] + hpart[3][tid] + b2[t];
        hout[(size_t)(brow0 + tid) * NMOD + t] = hv;
    }
}

// ---------------------------------------------------------------------------
// module2node: out[b][v] = sum_m Wm[v][m] * mask_m2n[b][v][m] * h[b][m] + bm[v]
// block = one b, 128 threads, lane-per-v: NO cross-lane reduction.
// 16B loads at 512B stride are line-covering over 4 consecutive iterations.
// ---------------------------------------------------------------------------
__global__ __launch_bounds__(128) void k_m2n(const float* __restrict__ m2n,
                                             const float* __restrict__ Wm,
                                             const float* __restrict__ bm,
                                             const float* __restrict__ h,
                                             float* __restrict__ out) {
    const int b = blockIdx.x;
    const int v = threadIdx.x;           // 0..127
    __shared__ float hs[NMOD];
    hs[v] = h[(size_t)b * NMOD + v];
    __syncthreads();

    const float4* mrow = (const float4*)(m2n + (size_t)b * (NVARS * NMOD) + (size_t)v * NMOD);
    const float4* wrow = (const float4*)(Wm + (size_t)v * NMOD);
    const float4* h4   = (const float4*)hs;

    float s = 0.f;
    #pragma unroll 8
    for (int mi = 0; mi < 32; ++mi) {
        float4 mm = mrow[mi];
        float4 wm = wrow[mi];
        float4 hv = h4[mi];
        s += wm.x * mm.x * hv.x + wm.y * mm.y * hv.y
           + wm.z * mm.z * hv.z + wm.w * mm.w * hv.w;
    }
    out[(size_t)b * NVARS + v] = s + bm[v];
}

// ---------------------------------------------------------------------------
extern "C" void kernel_launch(void* const* d_in, const int* in_sizes, int n_in,
                              void* d_out, int out_size, void* d_ws, size_t ws_size,
                              hipStream_t stream) {
    const float* x    = (const float*)d_in[0];
    const float* mn2m = (const float*)d_in[1];
    const float* mm2n = (const float*)d_in[2];
    const float* W0   = (const float*)d_in[3];
    const float* b0   = (const float*)d_in[4];
    const float* W1   = (const float*)d_in[5];
    const float* b1   = (const float*)d_in[6];
    const float* W2   = (const float*)d_in[7];
    const float* b2   = (const float*)d_in[8];
    const float* Wm   = (const float*)d_in[9];
    const float* bm   = (const float*)d_in[10];
    float* out = (float*)d_out;

    // workspace layout (bytes):
    //   Xm  bf16 [128][4096][128]  = 134,217,728
    //   W0b bf16 [128][256][128]   =   8,388,608
    //   W1b bf16 [128][256][256]   =  16,777,216
    //   h   f32  [4096][128]       =   2,097,152
    char* ws = (char*)d_ws;
    unsigned short* Xm   = (unsigned short*)(ws);
    unsigned short* W0b  = (unsigned short*)(ws + (size_t)134217728);
    unsigned short* W1b  = (unsigned short*)(ws + (size_t)142606336);
    float*          hbuf = (float*)(ws + (size_t)159383552);

    k_maskx<<<4096, 256, 0, stream>>>(mn2m, x, Xm);
    k_cvt  <<<4096, 256, 0, stream>>>(W0, (ushort4*)W0b, 1048576);
    k_cvt  <<<8192, 256, 0, stream>>>(W1, (ushort4*)W1b, 2097152);
    k_mlp  <<<dim3(64, 128), 256, 0, stream>>>(Xm, W0b, b0, W1b, b1, W2, b2, hbuf);
    k_m2n  <<<4096, 128, 0, stream>>>(mm2n, Wm, bm, hbuf, out);
}